// Round 5
// baseline (211.149 us; speedup 1.0000x reference)
//
#include <hip/hip_runtime.h>

namespace {

constexpr int B_  = 2;
constexpr int N_  = 512;
constexpr int IN_ = 512;
constexpr int M_  = 300;   // MEM
constexpr int H_  = 64;    // HID
constexpr float SLOPE_ = 0.01f;

// ---- workspace layout (float offsets). No atomics; every buffer fully
// written by plain stores before read. Split-K slices live in separate
// buffers and are folded by their consumers (A-side, W-side, or attn-stage).
constexpr long OFF_CW1AI = 0;                        // 300 x 64
constexpr long OFF_CW1AJ = OFF_CW1AI + 19200;
constexpr long OFF_BS1I  = OFF_CW1AJ + 19200;        // 64
constexpr long OFF_BS1J  = OFF_BS1I  + 64;
constexpr long OFF_H0S   = OFF_BS1J  + 64;           // 3 x (1024 x 300)
constexpr long OFF_SI0S  = OFF_H0S   + 3L * 307200;  // 4 x (1024 x 64)
constexpr long OFF_SJ0S  = OFF_SI0S  + 4L * 65536;
constexpr long OFF_F1S   = OFF_SJ0S  + 4L * 65536;   // 3 x (1024 x 300)
constexpr long OFF_H1S   = OFF_F1S   + 3L * 307200;  // 2 x (1024 x 300)
constexpr long OFF_SI1S  = OFF_H1S   + 2L * 307200;  // 2 x (1024 x 64)
constexpr long OFF_SJ1S  = OFF_SI1S  + 2L * 65536;
constexpr long OFF_ZP0   = OFF_SJ1S  + 2L * 65536;   // 2 x 256
constexpr long OFF_ZP1   = OFF_ZP0   + 512;
constexpr long OFF_P0    = OFF_ZP1   + 512;          // 2 x 512 x 512
constexpr long OFF_P1    = OFF_P0    + 524288;       // total ~21 MB

__device__ __forceinline__ float4 f4add(float4 a, float4 b) {
    a.x += b.x; a.y += b.y; a.z += b.z; a.w += b.w; return a;
}

// ---------------------------------------------------------------------------
// Multi-job GEMM, 4x4 micro-tile: both fragments are ONE ds_read_b128 each
// (1.5 LDS-cyc per 16 wave-FMA vs 2.95 for the old 2x4 — the LDS pipe is the
// measured bottleneck). A is staged k-major with XOR swizzle
// idx = row ^ (((k>>3)&3)<<2) so the strided staging stores are conflict-free
// and the b128 read at slot (tr^s)*4 returns rows tr*4..tr*4+3.
//   C[slice] = scale * (sum_s A[s]) @ (sum_s W[s]) + (slice==0 ? bias : 0)
// TPB=256 -> 64x64 tile; TPB=64 -> 32x32 tile (for dispatches short on tiles:
// active-CU count, not block size, divides the conserved LDS work).
// ---------------------------------------------------------------------------
struct JobsK {
    const float* A[5]; long afs[5];
    const float* W[5]; long wfs[5];
    const float* bias[5]; const float* Zp[5];
    float* C[5]; long cslice[5];
    int K[5]; int lda[5]; int Cc[5]; int R[5]; int split[5];
    int off[5]; int njobs;
};

template<int TPB, int AFOLD, int WFOLD>
__global__ __launch_bounds__(TPB)
void gemm_jobs(JobsK jb)
{
    constexpr int TM  = (TPB == 256) ? 64 : 32;
    constexpr int TN  = TM;
    constexpr int APT = 32 * TM / TPB;   // A floats/thread: 8 or 16
    constexpr int AQW = 32 / APT;        // threads per A-row: 4 or 2
    constexpr int WQW = TPB / 32;        // threads per W-k-row: 8 or 2
    constexpr int WPT = TN / WQW;        // W floats/thread: 8 or 16
    constexpr int TCW = TN / 4;          // col thread-groups: 16 or 8

    __shared__ __align__(16) float As[32][TM + 4];
    __shared__ __align__(16) float Ws[32][TN + 4];
    __shared__ float zred[4];

    const int bid = blockIdx.x;
    int j = jb.njobs - 1;
    while (j > 0 && bid < jb.off[j]) --j;
    const int local = bid - jb.off[j];

    const float* __restrict__ A = jb.A[j];  const long afs = jb.afs[j];
    const float* __restrict__ W = jb.W[j];  const long wfs = jb.wfs[j];
    const float* bias = jb.bias[j];
    const float* Zp   = jb.Zp[j];
    float* __restrict__ C = jb.C[j];
    const int K = jb.K[j], lda = jb.lda[j], Cc = jb.Cc[j], R = jb.R[j];
    const int split = jb.split[j];

    const int tx  = (Cc + TN - 1) / TN;
    const int ty  = (R + TM - 1) / TM;
    const int nrc = tx * ty;
    const int tile  = local % nrc;
    const int slice = local / nrc;
    const int row0 = (tile / tx) * TM;
    const int col0 = (tile % tx) * TN;
    const int nslab = (K + 31) >> 5;
    const int spl   = (nslab + split - 1) / split;
    const int kb    = slice * spl * 32;
    const int Ke    = min(K, kb + spl * 32);
    C += (long)slice * jb.cslice[j];

    const int t  = threadIdx.x;
    const int ar = t / AQW, aq = t % AQW;
    const int arow = min(row0 + ar, R - 1);
    const int wr = t / WQW, wq = t % WQW;
    const int tr = t / TCW, tc = t % TCW;

    float4 av[APT / 4], wv[WPT / 4];

    auto loadA = [&](int k0) {
        #pragma unroll
        for (int f = 0; f < APT / 4; ++f) {
            const int k = k0 + aq * APT + f * 4;
            const long base = (long)arow * lda + k;
            float4 r = make_float4(0.f, 0.f, 0.f, 0.f);
            if (k + 3 < Ke) {
                #pragma unroll
                for (int s = 0; s < AFOLD; ++s)
                    r = f4add(r, *(const float4*)(A + (long)s * afs + base));
            } else {
                #pragma unroll
                for (int u = 0; u < 4; ++u)
                    if (k + u < Ke) {
                        float v = 0.f;
                        #pragma unroll
                        for (int s = 0; s < AFOLD; ++s)
                            v += A[(long)s * afs + base + u];
                        (&r.x)[u] = v;
                    }
            }
            av[f] = r;
        }
    };
    auto loadW = [&](int k0) {
        const int gk = k0 + wr;
        #pragma unroll
        for (int f = 0; f < WPT / 4; ++f) {
            const int c = col0 + wq * WPT + f * 4;
            float4 r = make_float4(0.f, 0.f, 0.f, 0.f);
            if (gk < Ke) {
                const long base = (long)gk * Cc + c;
                if (c + 3 < Cc) {
                    #pragma unroll
                    for (int s = 0; s < WFOLD; ++s)
                        r = f4add(r, *(const float4*)(W + (long)s * wfs + base));
                } else {
                    #pragma unroll
                    for (int u = 0; u < 4; ++u)
                        if (c + u < Cc) {
                            float v = 0.f;
                            #pragma unroll
                            for (int s = 0; s < WFOLD; ++s)
                                v += W[(long)s * wfs + base + u];
                            (&r.x)[u] = v;
                        }
                }
            }
            wv[f] = r;
        }
    };

    float acc[4][4] = {};
    loadA(kb);
    loadW(kb);

    for (int k0 = kb; k0 < Ke; k0 += 32) {
        #pragma unroll
        for (int f = 0; f < APT / 4; ++f) {
            #pragma unroll
            for (int c = 0; c < 4; ++c) {
                const int kk = aq * APT + f * 4 + c;
                const int s  = (kk >> 3) & 3;
                As[kk][ar ^ (s << 2)] = (&av[f].x)[c];
            }
        }
        #pragma unroll
        for (int f = 0; f < WPT / 4; ++f)
            *(float4*)&Ws[wr][wq * WPT + 4 * f] = wv[f];
        __syncthreads();

        if (k0 + 32 < Ke) {                // prefetch next slab behind compute
            loadA(k0 + 32);
            loadW(k0 + 32);
        }

        #pragma unroll
        for (int k = 0; k < 32; ++k) {
            const int s = (k >> 3) & 3;
            const float4 a4 = *(const float4*)&As[k][(tr ^ s) * 4];
            const float4 w4 = *(const float4*)&Ws[k][tc * 4];
            const float a_[4] = {a4.x, a4.y, a4.z, a4.w};
            #pragma unroll
            for (int i = 0; i < 4; ++i) {
                acc[i][0] = fmaf(a_[i], w4.x, acc[i][0]);
                acc[i][1] = fmaf(a_[i], w4.y, acc[i][1]);
                acc[i][2] = fmaf(a_[i], w4.z, acc[i][2]);
                acc[i][3] = fmaf(a_[i], w4.w, acc[i][3]);
            }
        }
        __syncthreads();
    }

    float scale = 1.0f;
    if (Zp != nullptr) {                   // softmax denom (256 partials)
        if constexpr (TPB == 256) {
            float v = Zp[t];
            #pragma unroll
            for (int off = 32; off > 0; off >>= 1)
                v += __shfl_down(v, off, 64);
            if ((t & 63) == 0) zred[t >> 6] = v;
            __syncthreads();
            scale = 1.0f / (zred[0] + zred[1] + zred[2] + zred[3]);
        } else {
            float v = Zp[t] + Zp[t + 64] + Zp[t + 128] + Zp[t + 192];
            #pragma unroll
            for (int off = 32; off > 0; off >>= 1)
                v += __shfl_down(v, off, 64);
            scale = 1.0f / __shfl(v, 0, 64);
        }
    }

    const int cbase = col0 + tc * 4;
    float bv[4] = {0.f, 0.f, 0.f, 0.f};
    if (bias != nullptr && slice == 0) {
        #pragma unroll
        for (int u = 0; u < 4; ++u)
            if (cbase + u < Cc) bv[u] = bias[cbase + u];
    }
    #pragma unroll
    for (int i = 0; i < 4; ++i) {
        const int r = row0 + tr * 4 + i;
        if (r < R) {
            if (cbase + 3 < Cc) {
                float4 o;
                o.x = fmaf(acc[i][0], scale, bv[0]);
                o.y = fmaf(acc[i][1], scale, bv[1]);
                o.z = fmaf(acc[i][2], scale, bv[2]);
                o.w = fmaf(acc[i][3], scale, bv[3]);
                *(float4*)(C + (long)r * Cc + cbase) = o;
            } else {
                #pragma unroll
                for (int u = 0; u < 4; ++u)
                    if (cbase + u < Cc)
                        C[(long)r * Cc + cbase + u] = fmaf(acc[i][u], scale, bv[u]);
            }
        }
    }
}

// ---------------------------------------------------------------------------
// Attention numerator tile (32i x 32j), FOLD si/sj slices at staging.
// VALU-bound (not LDS-bound) — unchanged from the proven round-3 kernel.
// ---------------------------------------------------------------------------
template<int FOLD>
__global__ __launch_bounds__(256)
void attn_k(const float* __restrict__ si, const float* __restrict__ sj,
            const float* __restrict__ adj, const float* __restrict__ a2w,
            const float* __restrict__ a2b, float* __restrict__ p,
            float* __restrict__ Zpart)
{
    __shared__ __align__(16) float Si[32][68];
    __shared__ __align__(16) float Sj[32][68];
    __shared__ float red[4];

    const int g    = blockIdx.x;          // 512 = 2b x 16it x 16jt
    const int b    = g >> 8;
    const int tile = g & 255;
    const int i0 = (tile >> 4) * 32;
    const int j0 = (tile & 15) * 32;
    const int t  = threadIdx.x;

    {   // stage 32x64 tiles (summing FOLD slices)
        const int r  = t >> 3;
        const int hc = (t & 7) * 8;
        const long gib = ((long)(b * N_ + i0 + r)) * H_ + hc;
        const long gjb = ((long)(b * N_ + j0 + r)) * H_ + hc;
        float4 a0 = make_float4(0.f, 0.f, 0.f, 0.f);
        float4 a1 = a0, b0v = a0, b1v = a0;
        #pragma unroll
        for (int s = 0; s < FOLD; ++s) {
            const float* gi = si + (long)s * 65536 + gib;
            const float* gj = sj + (long)s * 65536 + gjb;
            a0  = f4add(a0,  *(const float4*)(gi));
            a1  = f4add(a1,  *(const float4*)(gi + 4));
            b0v = f4add(b0v, *(const float4*)(gj));
            b1v = f4add(b1v, *(const float4*)(gj + 4));
        }
        *(float4*)&Si[r][hc]     = a0;
        *(float4*)&Si[r][hc + 4] = a1;
        *(float4*)&Sj[r][hc]     = b0v;
        *(float4*)&Sj[r][hc + 4] = b1v;
    }
    __syncthreads();

    const int i  = t >> 3;
    const int jl = t & 7;

    float e[4] = {0.f, 0.f, 0.f, 0.f};
    #pragma unroll
    for (int h0 = 0; h0 < H_; h0 += 4) {
        const float4 a4 = *(const float4*)&Si[i][h0];
        const float w0v = a2w[h0 + 0];
        const float w1v = a2w[h0 + 1];
        const float w2v = a2w[h0 + 2];
        const float w3v = a2w[h0 + 3];
        #pragma unroll
        for (int u = 0; u < 4; ++u) {
            const float4 b4 = *(const float4*)&Sj[jl + 8 * u][h0];
            e[u] = fmaf(fmaxf(a4.x + b4.x, 0.f), w0v, e[u]);
            e[u] = fmaf(fmaxf(a4.y + b4.y, 0.f), w1v, e[u]);
            e[u] = fmaf(fmaxf(a4.z + b4.z, 0.f), w2v, e[u]);
            e[u] = fmaf(fmaxf(a4.w + b4.w, 0.f), w3v, e[u]);
        }
    }

    const float a2bv = a2b[0];
    const long rowbase = ((long)(b * N_ + i0 + i)) * N_ + j0 + jl;
    float lsum = 0.f;
    #pragma unroll
    for (int u = 0; u < 4; ++u) {
        float ev = e[u] + a2bv;
        ev = (ev >= 0.f) ? ev : SLOPE_ * ev;
        const float m  = adj[rowbase + 8 * u];
        const float pv = m * __expf(ev);
        p[rowbase + 8 * u] = pv;
        lsum += pv;
    }

    #pragma unroll
    for (int off = 32; off > 0; off >>= 1)
        lsum += __shfl_down(lsum, off, 64);
    if ((t & 63) == 0) red[t >> 6] = lsum;
    __syncthreads();
    if (t == 0)
        Zpart[b * 256 + tile] = red[0] + red[1] + red[2] + red[3];
}

} // namespace

extern "C" void kernel_launch(void* const* d_in, const int* in_sizes, int n_in,
                              void* d_out, int out_size, void* d_ws, size_t ws_size,
                              hipStream_t stream)
{
    (void)in_sizes; (void)n_in; (void)out_size; (void)ws_size;
    const float* feature = (const float*)d_in[0];
    const float* adj     = (const float*)d_in[1];
    const float* w0      = (const float*)d_in[2];
    const float* b0      = (const float*)d_in[3];
    const float* w1      = (const float*)d_in[4];
    const float* b1      = (const float*)d_in[5];
    const float* a1w     = (const float*)d_in[6];   // (600, 64) row-major
    const float* a1b     = (const float*)d_in[7];
    const float* a2w     = (const float*)d_in[8];
    const float* a2b     = (const float*)d_in[9];
    float* out = (float*)d_out;
    float* ws  = (float*)d_ws;

    float* cW1Ai = ws + OFF_CW1AI;
    float* cW1Aj = ws + OFF_CW1AJ;
    float* bs1i  = ws + OFF_BS1I;
    float* bs1j  = ws + OFF_BS1J;
    float* h0s   = ws + OFF_H0S;    // 3 slices
    float* si0s  = ws + OFF_SI0S;   // 4 slices
    float* sj0s  = ws + OFF_SJ0S;   // 4 slices
    float* f1s   = ws + OFF_F1S;    // 3 slices
    float* h1s   = ws + OFF_H1S;    // 2 slices
    float* si1s  = ws + OFF_SI1S;   // 2 slices
    float* sj1s  = ws + OFF_SJ1S;   // 2 slices
    float* Zp0   = ws + OFF_ZP0;
    float* Zp1   = ws + OFF_ZP1;
    float* p0    = ws + OFF_P0;
    float* p1    = ws + OFF_P1;

    const float* Ai = a1w;                    // top half (300 x 64)
    const float* Aj = a1w + (long)M_ * H_;    // bottom half

    auto set_job = [](JobsK& jb, int j, const float* A, long afs,
                      const float* W, long wfs, const float* bias,
                      const float* Zp, float* C, long cslice,
                      int K, int lda, int Cc, int R, int split,
                      int TM, int& tiles) {
        jb.A[j] = A; jb.afs[j] = afs;
        jb.W[j] = W; jb.wfs[j] = wfs;
        jb.bias[j] = bias; jb.Zp[j] = Zp;
        jb.C[j] = C; jb.cslice[j] = cslice;
        jb.K[j] = K; jb.lda[j] = lda; jb.Cc[j] = Cc; jb.R[j] = R;
        jb.split[j] = split;
        jb.off[j] = tiles;
        tiles += ((R + TM - 1) / TM) * ((Cc + TM - 1) / TM) * split;
    };

    // ---- D1: h0 slices (split 3) + layer-1 fused weights (252 blocks) ----
    {
        JobsK jb; int tiles = 0;
        set_job(jb, 0, feature, 0, w0, 0, b0, nullptr, h0s, 307200,
                IN_, IN_, M_, 1024, 3, 64, tiles);                   // 240
        set_job(jb, 1, w1, 0, Ai, 0, nullptr, nullptr, cW1Ai, 0,
                M_, M_, H_, M_, 1, 64, tiles);                       // 5
        set_job(jb, 2, w1, 0, Aj, 0, nullptr, nullptr, cW1Aj, 0,
                M_, M_, H_, M_, 1, 64, tiles);                       // 5
        set_job(jb, 3, b1, 0, Ai, 0, nullptr, nullptr, bs1i, 0,
                M_, M_, H_, 1, 1, 64, tiles);                        // 1
        set_job(jb, 4, b1, 0, Aj, 0, a1b, nullptr, bs1j, 0,
                M_, M_, H_, 1, 1, 64, tiles);                        // 1
        jb.njobs = 5;
        gemm_jobs<256, 1, 1><<<dim3(tiles), dim3(256), 0, stream>>>(jb);
    }

    // ---- D2: si0/sj0 slices = (sum 3 h0 slices)@{Ai,Aj} (128 blocks) ----
    {
        JobsK jb; int tiles = 0;
        set_job(jb, 0, h0s, 307200, Ai, 0, nullptr, nullptr, si0s, 65536,
                M_, M_, H_, 1024, 4, 64, tiles);                     // 64
        set_job(jb, 1, h0s, 307200, Aj, 0, a1b, nullptr, sj0s, 65536,
                M_, M_, H_, 1024, 4, 64, tiles);                     // 64
        jb.njobs = 2;
        gemm_jobs<256, 3, 1><<<dim3(tiles), dim3(256), 0, stream>>>(jb);
    }

    // ---- D3: attn0 (fold 4) -> p0, Zp0 (512 blocks) ----
    attn_k<4><<<dim3(512), dim3(256), 0, stream>>>(
        si0s, sj0s, adj, a2w, a2b, p0, Zp0);

    // ---- D4: f1 slices (split 3) = (1/Z0)*p0@(sum 3 h0 slices) (240) ----
    {
        JobsK jb; int tiles = 0;
        set_job(jb, 0, p0, 0, h0s, 307200, nullptr, Zp0, f1s, 307200,
                N_, N_, M_, N_, 3, 64, tiles);                       // 120
        set_job(jb, 1, p0 + 262144, 0, h0s + 153600, 307200, nullptr,
                Zp0 + 256, f1s + 153600, 307200,
                N_, N_, M_, N_, 3, 64, tiles);                       // 120
        jb.njobs = 2;
        gemm_jobs<256, 1, 3><<<dim3(tiles), dim3(256), 0, stream>>>(jb);
    }

    // ---- D5: h1/si1/sj1 slices = (sum 3 f1 slices)@{w1,cW1Ai,cW1Aj} (224) ----
    {
        JobsK jb; int tiles = 0;
        set_job(jb, 0, f1s, 307200, w1, 0, b1, nullptr, h1s, 307200,
                M_, M_, M_, 1024, 2, 64, tiles);                     // 160
        set_job(jb, 1, f1s, 307200, cW1Ai, 0, bs1i, nullptr, si1s, 65536,
                M_, M_, H_, 1024, 2, 64, tiles);                     // 32
        set_job(jb, 2, f1s, 307200, cW1Aj, 0, bs1j, nullptr, sj1s, 65536,
                M_, M_, H_, 1024, 2, 64, tiles);                     // 32
        jb.njobs = 3;
        gemm_jobs<256, 3, 1><<<dim3(tiles), dim3(256), 0, stream>>>(jb);
    }

    // ---- D6: attn1 (fold 2) -> p1, Zp1 (512 blocks) ----
    attn_k<2><<<dim3(512), dim3(256), 0, stream>>>(
        si1s, sj1s, adj, a2w, a2b, p1, Zp1);

    // ---- D7: out = (1/Z1)*p1@(sum 2 h1 slices), 64-thr 32x32 tiles (320) ----
    {
        JobsK jb; int tiles = 0;
        set_job(jb, 0, p1, 0, h1s, 307200, nullptr, Zp1, out, 0,
                N_, N_, M_, N_, 1, 32, tiles);                       // 160
        set_job(jb, 1, p1 + 262144, 0, h1s + 153600, 307200, nullptr,
                Zp1 + 256, out + 153600, 0,
                N_, N_, M_, N_, 1, 32, tiles);                       // 160
        jb.njobs = 2;
        gemm_jobs<64, 1, 2><<<dim3(tiles), dim3(64), 0, stream>>>(jb);
    }
}